// Round 10
// baseline (168.563 us; speedup 1.0000x reference)
//
#include <hip/hip_runtime.h>
#include <hip/hip_bf16.h>

#define DDIM 448
#define NSTEP 14            // 448 / 32

typedef __hip_bfloat16 bf16;
typedef __attribute__((ext_vector_type(8))) short short8;   // 8 bf16 = 16B (MFMA A/B frag)
typedef __attribute__((ext_vector_type(4))) float f32x4;    // MFMA C/D frag / float4

__device__ __forceinline__ short bf_bits(float f) {
    bf16 h = __float2bfloat16(f);
    return *reinterpret_cast<short*>(&h);
}

// ---------------------------------------------------------------------------
// Kernel 1: fused weight  E[i][d] = Wq*diagA + Wk*diagB + Wv*diagC,
//           Wc[i][o] = sum_d E[i][d] * Wo[d][o].
// Output layout (verified): Wt[s][o][k] = Wc[s*32+k][o] — each lane's GEMM
// B-fragment is 16 contiguous bytes.  UNCHANGED.
// ---------------------------------------------------------------------------
__global__ __launch_bounds__(256) void prep_wc(
    const float* __restrict__ Wq, const float* __restrict__ Wk,
    const float* __restrict__ Wv, const float* __restrict__ Wo,
    const float* __restrict__ Ad, const float* __restrict__ Bd,
    const float* __restrict__ Cd, bf16* __restrict__ Wt)
{
    __shared__ __align__(16) bf16 As[64 * 32];
    __shared__ __align__(16) bf16 Bs[64 * 32];
    __shared__ float da[DDIM], db[DDIM], dc[DDIM];

    const int tid  = threadIdx.x;
    const int i0   = blockIdx.x * 64;
    const int o0   = blockIdx.y * 64;
    const int lane = tid & 63;
    const int wid  = tid >> 6;
    const int wm   = wid >> 1, wn = wid & 1;
    const int m_   = lane & 15, kq = lane >> 4;

    for (int d = tid; d < DDIM; d += 256) {
        da[d] = Ad[d * DDIM + d];
        db[d] = Bd[d * DDIM + d];
        dc[d] = Cd[d * DDIM + d];
    }

    const int dr  = tid >> 3;
    const int oc8 = (tid & 7) * 8;
    const int ir  = tid >> 2;
    const int dc8 = (tid & 3) * 8;

    f32x4 acc[2][2] = {};

    f32x4 w0 = *(const f32x4*)(Wo + dr * DDIM + o0 + oc8);
    f32x4 w1 = *(const f32x4*)(Wo + dr * DDIM + o0 + oc8 + 4);
    f32x4 q0 = *(const f32x4*)(Wq + (i0 + ir) * DDIM + dc8);
    f32x4 q1 = *(const f32x4*)(Wq + (i0 + ir) * DDIM + dc8 + 4);
    f32x4 t0 = *(const f32x4*)(Wk + (i0 + ir) * DDIM + dc8);
    f32x4 t1 = *(const f32x4*)(Wk + (i0 + ir) * DDIM + dc8 + 4);
    f32x4 v0 = *(const f32x4*)(Wv + (i0 + ir) * DDIM + dc8);
    f32x4 v1 = *(const f32x4*)(Wv + (i0 + ir) * DDIM + dc8 + 4);

    for (int k0 = 0; k0 < DDIM; k0 += 32) {
        __syncthreads();
        #pragma unroll
        for (int j = 0; j < 4; ++j) {
            As[(oc8 + j) * 32 + dr]     = __float2bfloat16(w0[j]);
            As[(oc8 + 4 + j) * 32 + dr] = __float2bfloat16(w1[j]);
        }
        short8 e;
        #pragma unroll
        for (int j = 0; j < 4; ++j) {
            e[j]     = bf_bits(q0[j] * da[k0 + dc8 + j]
                             + t0[j] * db[k0 + dc8 + j]
                             + v0[j] * dc[k0 + dc8 + j]);
            e[j + 4] = bf_bits(q1[j] * da[k0 + dc8 + 4 + j]
                             + t1[j] * db[k0 + dc8 + 4 + j]
                             + v1[j] * dc[k0 + dc8 + 4 + j]);
        }
        *(short8*)&Bs[ir * 32 + dc8] = e;
        __syncthreads();

        const int kn = (k0 + 32 < DDIM) ? k0 + 32 : 0;
        w0 = *(const f32x4*)(Wo + (kn + dr) * DDIM + o0 + oc8);
        w1 = *(const f32x4*)(Wo + (kn + dr) * DDIM + o0 + oc8 + 4);
        q0 = *(const f32x4*)(Wq + (i0 + ir) * DDIM + kn + dc8);
        q1 = *(const f32x4*)(Wq + (i0 + ir) * DDIM + kn + dc8 + 4);
        t0 = *(const f32x4*)(Wk + (i0 + ir) * DDIM + kn + dc8);
        t1 = *(const f32x4*)(Wk + (i0 + ir) * DDIM + kn + dc8 + 4);
        v0 = *(const f32x4*)(Wv + (i0 + ir) * DDIM + kn + dc8);
        v1 = *(const f32x4*)(Wv + (i0 + ir) * DDIM + kn + dc8 + 4);

        short8 af[2], bfr[2];
        #pragma unroll
        for (int mi = 0; mi < 2; ++mi)
            af[mi] = *(const short8*)&As[(wm * 32 + mi * 16 + m_) * 32 + kq * 8];
        #pragma unroll
        for (int ni = 0; ni < 2; ++ni)
            bfr[ni] = *(const short8*)&Bs[(wn * 32 + ni * 16 + m_) * 32 + kq * 8];
        #pragma unroll
        for (int mi = 0; mi < 2; ++mi)
            #pragma unroll
            for (int ni = 0; ni < 2; ++ni)
                acc[mi][ni] = __builtin_amdgcn_mfma_f32_16x16x32_bf16(
                    af[mi], bfr[ni], acc[mi][ni], 0, 0, 0);
    }

    #pragma unroll
    for (int mi = 0; mi < 2; ++mi)
        #pragma unroll
        for (int ni = 0; ni < 2; ++ni) {
            const int o = o0 + wm * 32 + mi * 16 + kq * 4;
            const int i = i0 + wn * 32 + ni * 16 + m_;
            bf16* dst = Wt + (i >> 5) * (DDIM * 32) + (i & 31);
            #pragma unroll
            for (int r = 0; r < 4; ++r)
                dst[(o + r) * 32] = __float2bfloat16(acc[mi][ni][r]);
        }
}

// ---------------------------------------------------------------------------
// Kernel 2: out[M x 448](fp32) = X(fp32) @ Wc.  B supplied as Wt[s][o][k].
// v10: BARRIER-FREE, LDS-FREE streaming MFMA. Rationale: all of v1-v9
// shared one structure — a per-K-step all-wave barrier + staged-LDS round
// trip — and every fix around it (occupancy, DMA shape, counted vmcnt,
// swizzle) moved <=2 µs; counters showed all pipes idle. The harness fills
// (8 VGPR, 8% occupancy, NO barriers) sustain 6.5 TB/s: continuous
// self-paced issue, not occupancy, is what saturates HBM.
//   * A-frags load DIRECTLY from X: lane (m_,kq) reads 32B fp32 at
//     X[row0+mi*16+m_][s*32+kq*8], cvt to bf16 in-lane. A wave-instr
//     touches 16 rows x one full 128B line each (all bytes used); the 4
//     column-waves re-reading those lines L2-hit. No A-LDS redistribution.
//   * B-frags load directly from L2-resident Wt (layout verified in v7):
//     bxp + ni*512 + s*14336, 1KB/wave-instr coalesced.
//   * Register pipeline: B double-buffered (bA/bB via 2-step unrolled
//     macro, static names — rule #20); A: f32 in-flight regs loaded at
//     step top, converted to af16 AFTER the MFMAs (~full step of slack
//     for the HBM latency), af16 carried into the next step.
//   * NO __syncthreads / s_barrier / waitcnt asm anywhere: compiler
//     inserts precise per-register waits; the 8 waves (2/SIMD) stream
//     independently and naturally desynchronize.
//   * Epilogue: v9-verified direct stores, fire-and-forget.
// VGPR ~ acc 112 + bA/bB 56 + af 16 + a-f32 32 + addr ~15 ≈ 231 -> fits
// __launch_bounds__(512,2) (<=256). LDS = 0.
// ---------------------------------------------------------------------------
__global__ __launch_bounds__(512, 2) void gemm_xwc(
    const float* __restrict__ X, const bf16* __restrict__ Wt,
    float* __restrict__ out)
{
    const int tid  = threadIdx.x;
    const int lane = tid & 63;
    const int wid  = tid >> 6;               // 0..7
    const int wr   = wid >> 2;               // row half
    const int wc   = wid & 3;                // col quarter
    const int m_   = lane & 15;
    const int kq   = lane >> 4;
    const int row0 = blockIdx.x * 128 + wr * 64;

    // A direct: lane (m_,kq), frag mi, step s reads 32B fp32 at
    //   X[(row0 + mi*16 + m_)][s*32 + kq*8]
    const float* axp = X + (row0 + m_) * DDIM + kq * 8;
    // B direct (v7-verified layout): frag ni, step s reads 16B at
    //   Wt + s*14336 + (wc*112 + ni*16 + m_)*32 + kq*8
    const bf16* bxp = Wt + (wc * 112 + m_) * 32 + kq * 8;

    f32x4 acc[4][7] = {};
    short8 af[4];                            // current-step A frags (bf16)
    short8 bA[7], bB[7];                     // B frag ping-pong
    f32x4 a0[4], a1[4];                      // in-flight A f32 (32 VGPR)

    // ---- prologue: A(0) f32 -> cvt -> af; B(0) -> bA
    #pragma unroll
    for (int mi = 0; mi < 4; ++mi) {
        a0[mi] = *(const f32x4*)(axp + mi * 16 * DDIM);
        a1[mi] = *(const f32x4*)(axp + mi * 16 * DDIM + 4);
    }
    #pragma unroll
    for (int ni = 0; ni < 7; ++ni)
        bA[ni] = *(const short8*)(bxp + ni * 512);
    #pragma unroll
    for (int mi = 0; mi < 4; ++mi)
        #pragma unroll
        for (int j = 0; j < 4; ++j) {
            af[mi][j]     = bf_bits(a0[mi][j]);
            af[mi][j + 4] = bf_bits(a1[mi][j]);
        }

// One K-step. S compile-time; BCUR/BNXT statically named (rule #20).
// Order: issue next-step loads | MFMA on current | cvt A(next) after MFMAs
// (WAR on af enforces cvt-after-MFMA; RAW gives next step's MFMAs the cvt).
#define GSTEP(S, BCUR, BNXT)                                                \
    {                                                                       \
        if ((S) + 1 < NSTEP) {                                              \
            const bf16* bs = bxp + ((S) + 1) * (DDIM * 32);                 \
            _Pragma("unroll")                                               \
            for (int ni = 0; ni < 7; ++ni)                                  \
                BNXT[ni] = *(const short8*)(bs + ni * 512);                 \
            const float* as = axp + ((S) + 1) * 32;                         \
            _Pragma("unroll")                                               \
            for (int mi = 0; mi < 4; ++mi) {                                \
                a0[mi] = *(const f32x4*)(as + mi * 16 * DDIM);              \
                a1[mi] = *(const f32x4*)(as + mi * 16 * DDIM + 4);          \
            }                                                               \
        }                                                                   \
        _Pragma("unroll")                                                   \
        for (int mi = 0; mi < 4; ++mi)                                      \
            _Pragma("unroll")                                               \
            for (int ni = 0; ni < 7; ++ni)                                  \
                acc[mi][ni] = __builtin_amdgcn_mfma_f32_16x16x32_bf16(      \
                    af[mi], BCUR[ni], acc[mi][ni], 0, 0, 0);                \
        if ((S) + 1 < NSTEP) {                                              \
            _Pragma("unroll")                                               \
            for (int mi = 0; mi < 4; ++mi)                                  \
                _Pragma("unroll")                                           \
                for (int j = 0; j < 4; ++j) {                               \
                    af[mi][j]     = bf_bits(a0[mi][j]);                     \
                    af[mi][j + 4] = bf_bits(a1[mi][j]);                     \
                }                                                           \
        }                                                                   \
    }

    #pragma unroll
    for (int ss = 0; ss < NSTEP; ss += 2) {
        GSTEP(ss,     bA, bB)
        GSTEP(ss + 1, bB, bA)
    }
#undef GSTEP

    // ---- epilogue: direct stores (v9-verified), fire-and-forget.
    {
        const int crow = row0 + kq * 4;
        const int ccol = wc * 112 + m_;
        #pragma unroll
        for (int mi = 0; mi < 4; ++mi)
            #pragma unroll
            for (int ni = 0; ni < 7; ++ni) {
                float* dst = out + (crow + mi * 16) * DDIM + ccol + ni * 16;
                #pragma unroll
                for (int r = 0; r < 4; ++r)
                    dst[r * DDIM] = acc[mi][ni][r];
            }
    }
}

// ---------------------------------------------------------------------------
extern "C" void kernel_launch(void* const* d_in, const int* in_sizes, int n_in,
                              void* d_out, int out_size, void* d_ws, size_t ws_size,
                              hipStream_t stream) {
    const float* x  = (const float*)d_in[0];
    const float* Wq = (const float*)d_in[1];
    const float* Wk = (const float*)d_in[2];
    const float* Wv = (const float*)d_in[3];
    const float* Wo = (const float*)d_in[4];
    const float* Ad = (const float*)d_in[5];
    const float* Bd = (const float*)d_in[6];
    const float* Cd = (const float*)d_in[7];

    bf16*  Wt  = (bf16*)d_ws;                      // 448*448*2 = 392 KiB scratch
    float* out = (float*)d_out;

    const int M = in_sizes[0] / DDIM;              // 32768

    prep_wc<<<dim3(7, 7), 256, 0, stream>>>(Wq, Wk, Wv, Wo, Ad, Bd, Cd, Wt);
    gemm_xwc<<<M / 128, 512, 0, stream>>>(x, Wt, out);
}

// Round 12
// 142.119 us; speedup vs baseline: 1.1861x; 1.1861x over previous
//
#include <hip/hip_runtime.h>
#include <hip/hip_bf16.h>

#define DDIM 448
#define NS2 7               // 448 / 64 K-macro-steps (BK=64)

typedef __hip_bfloat16 bf16;
typedef __attribute__((ext_vector_type(8))) short short8;   // 8 bf16 = 16B (MFMA A/B frag)
typedef __attribute__((ext_vector_type(4))) float f32x4;    // MFMA C/D frag / float4

__device__ __forceinline__ short bf_bits(float f) {
    bf16 h = __float2bfloat16(f);
    return *reinterpret_cast<short*>(&h);
}

// async global->LDS DMA: per-lane 16B; LDS dst = wave-uniform base + lane*16
__device__ __forceinline__ void async16(const bf16* g, bf16* l) {
    __builtin_amdgcn_global_load_lds(
        (const __attribute__((address_space(1))) void*)g,
        (__attribute__((address_space(3))) void*)l, 16, 0, 0);
}

// ---------------------------------------------------------------------------
// Kernel 1: fused weight  E[i][d] = Wq*diagA + Wk*diagB + Wv*diagC,
//           Wc[i][o] = sum_d E[i][d] * Wo[d][o].
// Output layout (verified): Wt[s][o][k] = Wc[s*32+k][o]; 28 KB contiguous
// per 32-wide slab; two adjacent slabs form a 56 KB BK=64 tile. UNCHANGED.
// ---------------------------------------------------------------------------
__global__ __launch_bounds__(256) void prep_wc(
    const float* __restrict__ Wq, const float* __restrict__ Wk,
    const float* __restrict__ Wv, const float* __restrict__ Wo,
    const float* __restrict__ Ad, const float* __restrict__ Bd,
    const float* __restrict__ Cd, bf16* __restrict__ Wt)
{
    __shared__ __align__(16) bf16 As[64 * 32];
    __shared__ __align__(16) bf16 Bs[64 * 32];
    __shared__ float da[DDIM], db[DDIM], dc[DDIM];

    const int tid  = threadIdx.x;
    const int i0   = blockIdx.x * 64;
    const int o0   = blockIdx.y * 64;
    const int lane = tid & 63;
    const int wid  = tid >> 6;
    const int wm   = wid >> 1, wn = wid & 1;
    const int m_   = lane & 15, kq = lane >> 4;

    for (int d = tid; d < DDIM; d += 256) {
        da[d] = Ad[d * DDIM + d];
        db[d] = Bd[d * DDIM + d];
        dc[d] = Cd[d * DDIM + d];
    }

    const int dr  = tid >> 3;
    const int oc8 = (tid & 7) * 8;
    const int ir  = tid >> 2;
    const int dc8 = (tid & 3) * 8;

    f32x4 acc[2][2] = {};

    f32x4 w0 = *(const f32x4*)(Wo + dr * DDIM + o0 + oc8);
    f32x4 w1 = *(const f32x4*)(Wo + dr * DDIM + o0 + oc8 + 4);
    f32x4 q0 = *(const f32x4*)(Wq + (i0 + ir) * DDIM + dc8);
    f32x4 q1 = *(const f32x4*)(Wq + (i0 + ir) * DDIM + dc8 + 4);
    f32x4 t0 = *(const f32x4*)(Wk + (i0 + ir) * DDIM + dc8);
    f32x4 t1 = *(const f32x4*)(Wk + (i0 + ir) * DDIM + dc8 + 4);
    f32x4 v0 = *(const f32x4*)(Wv + (i0 + ir) * DDIM + dc8);
    f32x4 v1 = *(const f32x4*)(Wv + (i0 + ir) * DDIM + dc8 + 4);

    for (int k0 = 0; k0 < DDIM; k0 += 32) {
        __syncthreads();
        #pragma unroll
        for (int j = 0; j < 4; ++j) {
            As[(oc8 + j) * 32 + dr]     = __float2bfloat16(w0[j]);
            As[(oc8 + 4 + j) * 32 + dr] = __float2bfloat16(w1[j]);
        }
        short8 e;
        #pragma unroll
        for (int j = 0; j < 4; ++j) {
            e[j]     = bf_bits(q0[j] * da[k0 + dc8 + j]
                             + t0[j] * db[k0 + dc8 + j]
                             + v0[j] * dc[k0 + dc8 + j]);
            e[j + 4] = bf_bits(q1[j] * da[k0 + dc8 + 4 + j]
                             + t1[j] * db[k0 + dc8 + 4 + j]
                             + v1[j] * dc[k0 + dc8 + 4 + j]);
        }
        *(short8*)&Bs[ir * 32 + dc8] = e;
        __syncthreads();

        const int kn = (k0 + 32 < DDIM) ? k0 + 32 : 0;
        w0 = *(const f32x4*)(Wo + (kn + dr) * DDIM + o0 + oc8);
        w1 = *(const f32x4*)(Wo + (kn + dr) * DDIM + o0 + oc8 + 4);
        q0 = *(const f32x4*)(Wq + (i0 + ir) * DDIM + kn + dc8);
        q1 = *(const f32x4*)(Wq + (i0 + ir) * DDIM + kn + dc8 + 4);
        t0 = *(const f32x4*)(Wk + (i0 + ir) * DDIM + kn + dc8);
        t1 = *(const f32x4*)(Wk + (i0 + ir) * DDIM + kn + dc8 + 4);
        v0 = *(const f32x4*)(Wv + (i0 + ir) * DDIM + kn + dc8);
        v1 = *(const f32x4*)(Wv + (i0 + ir) * DDIM + kn + dc8 + 4);

        short8 af[2], bfr[2];
        #pragma unroll
        for (int mi = 0; mi < 2; ++mi)
            af[mi] = *(const short8*)&As[(wm * 32 + mi * 16 + m_) * 32 + kq * 8];
        #pragma unroll
        for (int ni = 0; ni < 2; ++ni)
            bfr[ni] = *(const short8*)&Bs[(wn * 32 + ni * 16 + m_) * 32 + kq * 8];
        #pragma unroll
        for (int mi = 0; mi < 2; ++mi)
            #pragma unroll
            for (int ni = 0; ni < 2; ++ni)
                acc[mi][ni] = __builtin_amdgcn_mfma_f32_16x16x32_bf16(
                    af[mi], bfr[ni], acc[mi][ni], 0, 0, 0);
    }

    #pragma unroll
    for (int mi = 0; mi < 2; ++mi)
        #pragma unroll
        for (int ni = 0; ni < 2; ++ni) {
            const int o = o0 + wm * 32 + mi * 16 + kq * 4;
            const int i = i0 + wn * 32 + ni * 16 + m_;
            bf16* dst = Wt + (i >> 5) * (DDIM * 32) + (i & 31);
            #pragma unroll
            for (int r = 0; r < 4; ++r)
                dst[(o + r) * 32] = __float2bfloat16(acc[mi][ni][r]);
        }
}

// ---------------------------------------------------------------------------
// Kernel 2: out[M x 448](fp32) = X(fp32) @ Wc.  B supplied as Wt[s][o][k].
// v11 (resubmitted — R11 failed on container infra, no kernel verdict):
// v6 with BK=64 (7 macro-steps instead of 14). Evidence: v6 spends
// ~5,600 cy/step vs ~1,500 cy of work — ~70% is PER-STEP fixed overhead
// (barrier convoy, wait release, 256-CU same-slab L2 transient). v10
// proved LDS staging is necessary (direct-global frags = 16-line gathers,
// 2x worse) and barriers are not the structural cost. Halving the step
// count at unchanged occupancy (1 block/CU both ways — m132's occupancy
// objection doesn't apply) amortizes the overhead 2x: 56 MFMA/wave/step.
//   * B-tile/step = 2 adjacent 28 KB slabs = 56 KB CONTIGUOUS in Wt ->
//     7 linear 1 KB DMAs per wave, ALL 8 waves DMA. Double-buffered;
//     B(s+1) issued FIRST in step s (a zero-cost compiler fence
//     `"" ::: "memory"` pins DMA-before-X issue order — NOT
//     sched_barrier(0), which m141/R2 showed wrecks codegen), waited at
//     step end with vmcnt(4): X(s+2)'s 4 loads (newest) stay in flight.
//   * A staged via linear tid*32 ds_writes (uniform bank load, v6-style):
//     thread tid stages X row (tid>>1)&127, cols (tid>>8)*32+(tid&1)*16,
//     16 f32 -> 2 ds_write_b128 at bytes tid*32, tid*32+16.
//     (Identity check: tid*32 == (tid>>8)*8192 + ((tid>>1)&127)*64
//      + (tid&1)*32 — exactly the [g][row][k] frag-read image.)
//   * One lgkmcnt(0)+s_barrier per macro-step. Fully unrolled (7 steps).
//   * Epilogue: v9-verified direct stores, fire-and-forget.
// smem: A0 @0 (16K: [2][128][32]bf16), A1 @16K, B0 @32K (56K: [2][448][32]),
// B1 @88K. Total 147456 B (144 KB) -> 1 block/CU, 8 waves, 2/SIMD.
// ---------------------------------------------------------------------------
__global__ __launch_bounds__(512, 2) void gemm_xwc(
    const float* __restrict__ X, const bf16* __restrict__ Wt,
    float* __restrict__ out)
{
    __shared__ __align__(16) char smem[147456];         // 144 KB

    const int tid  = threadIdx.x;
    const int lane = tid & 63;
    const int wid  = tid >> 6;               // 0..7
    const int wr   = wid >> 2;               // row half: rows wr*64 + [0,64)
    const int wc   = wid & 3;                // col quarter: cols wc*112 + [0,112)
    const int m_   = lane & 15;
    const int kq   = lane >> 4;
    const int row0 = blockIdx.x * 128;

    // A staging: thread stages X[row (tid>>1)&127][kbase + (tid>>8)*32 +
    // (tid&1)*16 .. +16) -> LDS bytes tid*32, tid*32+16 (linear, uniform).
    const int arow = (tid >> 1) & 127;
    const int acol = (tid >> 8) * 32 + (tid & 1) * 16;
    const float* agp = X + (row0 + arow) * DDIM + acol;
    const int awb = tid * 32;                // byte offset within A buffer

    // B DMA: wave wid, instr j moves 1 KB linear; step tile = 56 KB contig
    const bf16* bgp = Wt + wid * 3584 + lane * 8;

    f32x4 acc[4][7] = {};
    f32x4 a0, a1, a2, a3;                    // in-flight X (16 f32)

    // ---- prologue -------------------------------------------------------
    a0 = *(const f32x4*)(agp);
    a1 = *(const f32x4*)(agp + 4);
    a2 = *(const f32x4*)(agp + 8);
    a3 = *(const f32x4*)(agp + 12);
    {   // stage A(0) (compiler inserts the X(0) wait)
        char* A0 = (char*)smem;
        short8 w0, w1;
        #pragma unroll
        for (int j = 0; j < 4; ++j) {
            w0[j] = bf_bits(a0[j]); w0[j + 4] = bf_bits(a1[j]);
            w1[j] = bf_bits(a2[j]); w1[j + 4] = bf_bits(a3[j]);
        }
        *(short8*)(A0 + awb)      = w0;
        *(short8*)(A0 + awb + 16) = w1;
    }
    {   // DMA B(0) -> B0
        bf16* B0 = (bf16*)(smem + 32768);
        #pragma unroll
        for (int j = 0; j < 7; ++j)
            async16(bgp + j * 512, B0 + wid * 3584 + j * 512);
    }
    asm volatile("" ::: "memory");           // pin: B(0) DMAs before X(1)
    a0 = *(const f32x4*)(agp + 64);          // X(1)
    a1 = *(const f32x4*)(agp + 68);
    a2 = *(const f32x4*)(agp + 72);
    a3 = *(const f32x4*)(agp + 76);
    asm volatile("s_waitcnt vmcnt(4)" ::: "memory");   // B(0) done; X(1) flies
    asm volatile("s_waitcnt lgkmcnt(0)" ::: "memory");
    __builtin_amdgcn_s_barrier();

    #pragma unroll
    for (int s = 0; s < NS2; ++s) {
        const char* AcB = (const char*)smem + (s & 1) * 16384 + wr * 4096;
        const char* BcB = (const char*)smem + 32768 + (s & 1) * 57344 + wc * 7168;

        // 1. DMA B(s+1) into the freed buffer (fenced before X loads)
        if (s + 1 < NS2) {
            bf16* Bn = (bf16*)(smem + 32768 + ((s + 1) & 1) * 57344);
            const bf16* bsrc = bgp + (s + 1) * 28672;
            #pragma unroll
            for (int j = 0; j < 7; ++j)
                async16(bsrc + j * 512, Bn + wid * 3584 + j * 512);
        }
        asm volatile("" ::: "memory");        // pin DMA-before-X issue order
        // 2. stage A(s+1) from a-regs (loaded last step / prologue)
        if (s + 1 < NS2) {
            char* An = (char*)smem + (((s + 1) & 1)) * 16384;
            short8 w0, w1;
            #pragma unroll
            for (int j = 0; j < 4; ++j) {
                w0[j] = bf_bits(a0[j]); w0[j + 4] = bf_bits(a1[j]);
                w1[j] = bf_bits(a2[j]); w1[j + 4] = bf_bits(a3[j]);
            }
            *(short8*)(An + awb)      = w0;
            *(short8*)(An + awb + 16) = w1;
        }
        // 3. load X(s+2)
        if (s + 2 < NS2) {
            const int k2 = (s + 2) * 64;
            a0 = *(const f32x4*)(agp + k2);
            a1 = *(const f32x4*)(agp + k2 + 4);
            a2 = *(const f32x4*)(agp + k2 + 8);
            a3 = *(const f32x4*)(agp + k2 + 12);
        }

        // 4. two K=32 groups: frag reads + MFMA (g1 reads hide under g0 MFMAs)
        #pragma unroll
        for (int g = 0; g < 2; ++g) {
            short8 af[4], bfr[7];
            #pragma unroll
            for (int mi = 0; mi < 4; ++mi)
                af[mi] = *(const short8*)(AcB + g * 8192 + mi * 1024
                                          + m_ * 64 + kq * 16);
            #pragma unroll
            for (int ni = 0; ni < 7; ++ni)
                bfr[ni] = *(const short8*)(BcB + g * 28672 + ni * 1024
                                           + m_ * 64 + kq * 16);
            #pragma unroll
            for (int mi = 0; mi < 4; ++mi)
                #pragma unroll
                for (int ni = 0; ni < 7; ++ni)
                    acc[mi][ni] = __builtin_amdgcn_mfma_f32_16x16x32_bf16(
                        af[mi], bfr[ni], acc[mi][ni], 0, 0, 0);
        }

        // 5. counted wait: retire B(s+1); keep X(s+2) (4 newest) in flight
        if (s + 2 < NS2) {
            asm volatile("s_waitcnt vmcnt(4)" ::: "memory");
        } else {
            asm volatile("s_waitcnt vmcnt(0)" ::: "memory");
        }
        asm volatile("s_waitcnt lgkmcnt(0)" ::: "memory");
        __builtin_amdgcn_s_barrier();
    }

    // ---- epilogue: direct stores (v9-verified), fire-and-forget.
    {
        const int crow = row0 + wr * 64 + kq * 4;
        const int ccol = wc * 112 + m_;
        #pragma unroll
        for (int mi = 0; mi < 4; ++mi)
            #pragma unroll
            for (int ni = 0; ni < 7; ++ni) {
                float* dst = out + (crow + mi * 16) * DDIM + ccol + ni * 16;
                #pragma unroll
                for (int r = 0; r < 4; ++r)
                    dst[r * DDIM] = acc[mi][ni][r];
            }
    }
}

// ---------------------------------------------------------------------------
extern "C" void kernel_launch(void* const* d_in, const int* in_sizes, int n_in,
                              void* d_out, int out_size, void* d_ws, size_t ws_size,
                              hipStream_t stream) {
    const float* x  = (const float*)d_in[0];
    const float* Wq = (const float*)d_in[1];
    const float* Wk = (const float*)d_in[2];
    const float* Wv = (const float*)d_in[3];
    const float* Wo = (const float*)d_in[4];
    const float* Ad = (const float*)d_in[5];
    const float* Bd = (const float*)d_in[6];
    const float* Cd = (const float*)d_in[7];

    bf16*  Wt  = (bf16*)d_ws;                      // 448*448*2 = 392 KiB scratch
    float* out = (float*)d_out;

    const int M = in_sizes[0] / DDIM;              // 32768

    prep_wc<<<dim3(7, 7), 256, 0, stream>>>(Wq, Wk, Wv, Wo, Ad, Bd, Cd, Wt);
    gemm_xwc<<<M / 128, 512, 0, stream>>>(x, Wt, out);
}